// Round 15
// baseline (202.298 us; speedup 1.0000x reference)
//
#include <hip/hip_runtime.h>

// ActorGCN collapsed-linear, dst-bucketed atomic-free pipeline, 7 dispatches.
// Identity: A(xW) = (Ax)W; BN stats of h = yW+b reduce to the 20x20
// covariance of y = A x. Hidden [N,1024] never materialized.
//
// Round 15: the edge scatter (4.16M global f32 atomics, random dst order,
// 16.6MB dest > 4MB XCD-L2 -> L2-miss RMW per atomic) and the separate
// stats pass are replaced by dst-bucketed aggregation:
//   - edges bucketed by dst chunk (256 rows / 20KB of y per bucket)
//   - k_tile: block owns its chunk EXCLUSIVELY -> accumulates edges into an
//     LDS tile via LDS atomics (no global RMW), adds self-term, writes y
//     once (streaming), computes the 230 moments from the same LDS tile.
//   Global f32 atomics: 4.16M -> 0. Stats read-pass: eliminated. z-zero:
//   eliminated.
// Pipeline: K1 init | K2 deg+count histograms | K3 scan(814) | K4 bucket
// fill | K5 tile(+stats) | K6 finalize | K7 out.
//
// Workspace: deg N | y 20N | stats 256 | params 64 (floats), then
// counts NB | bstart NB+1 | cursor NB | ebuf E (ints). NB = ceil(N/256).

#define F 20
#define NSTAT 230
#define SROWS 256
#define BSZ 256

__global__ void k_init(float* __restrict__ deg, float* __restrict__ stats,
                       int* __restrict__ counts, int N, int NB) {
  int i = blockIdx.x * blockDim.x + threadIdx.x;
  if (i < N) deg[i] = 0.f;  // self-loop added at use: deg_true = deg + 1
  if (i < 256) stats[i] = 0.f;
  if (i < NB) counts[i] = 0;
}

// degree histogram (float) + per-chunk edge-count histogram (int).
__global__ void k_deg_count(const int* __restrict__ dst, float* __restrict__ deg,
                            int* __restrict__ counts, int E) {
  int e = blockIdx.x * blockDim.x + threadIdx.x;
  if (e >= E) return;
  int d = dst[e];
  atomicAdd(&deg[d], 1.0f);
  atomicAdd(&counts[d >> 8], 1);
}

// exclusive scan of NB (<=1024) bucket counts, single block of 1024.
__global__ __launch_bounds__(1024) void k_scan(const int* __restrict__ counts,
                                               int* __restrict__ bstart,
                                               int* __restrict__ cursor,
                                               int NB, int E) {
  __shared__ int s[1024];
  int t = threadIdx.x;
  int c = (t < NB) ? counts[t] : 0;
  s[t] = c;
  __syncthreads();
  for (int off = 1; off < 1024; off <<= 1) {
    int v = (t >= off) ? s[t - off] : 0;
    __syncthreads();
    s[t] += v;
    __syncthreads();
  }
  if (t < NB) {
    int excl = s[t] - c;
    bstart[t] = excl;
    cursor[t] = excl;
  }
  if (t == 0) bstart[NB] = E;
}

// scatter edge ids into dst-chunk buckets.
__global__ void k_fill(const int* __restrict__ dst, int* __restrict__ cursor,
                       int* __restrict__ ebuf, int E) {
  int e = blockIdx.x * blockDim.x + threadIdx.x;
  if (e >= E) return;
  int c = dst[e] >> 8;
  int pos = atomicAdd(&cursor[c], 1);
  ebuf[pos] = e;
}

// Block b owns dst rows [b*256, b*256+256): accumulate its bucket's edges
// into an LDS tile (LDS atomics, f-major items -> coalesced x reads), add
// self-term, write y_full once, compute stats from the LDS tile.
__global__ __launch_bounds__(BSZ) void k_tile(
    const int* __restrict__ src, const int* __restrict__ dst,
    const int* __restrict__ bstart, const int* __restrict__ ebuf,
    const float* __restrict__ deg,
    const float* __restrict__ state, const float* __restrict__ edge_attr,
    float* __restrict__ y, float* __restrict__ stats, int N, int Ns) {
  __shared__ float tile[SROWS * F];  // 20 KB
  int t = threadIdx.x;

  for (int i4 = t; i4 < SROWS * 5; i4 += BSZ)
    *reinterpret_cast<float4*>(tile + i4 * 4) = make_float4(0.f, 0.f, 0.f, 0.f);
  __syncthreads();

  // ---- edge accumulation into LDS (z-part: sum dinv[s]*x[s]) ----
  int start = bstart[blockIdx.x];
  int cnt = bstart[blockIdx.x + 1] - start;
  int sb = Ns * F;
  int nit = cnt * F;
  for (int it = t; it < nit; it += BSZ) {
    int le = it / F;
    int f = it - le * F;
    int e = ebuf[start + le];
    int s = src[e];
    int d = dst[e];
    float ns = rsqrtf(deg[s] + 1.0f);
    int xi = s * F + f;
    float x = (xi < sb) ? state[xi] : edge_attr[xi - sb];
    atomicAdd(&tile[(d & (SROWS - 1)) * F + f], ns * x);
  }
  __syncthreads();

  // ---- self-term + finalize rows: y_full = dinv*(z + dinv*x); writeback ----
  long rowbase = (long)blockIdx.x * SROWS;
  for (int i4 = t; i4 < SROWS * 5; i4 += BSZ) {
    int rl = i4 / 5;
    int q = i4 - rl * 5;
    long row = rowbase + rl;
    float4 v = make_float4(0.f, 0.f, 0.f, 0.f);
    if (row < N) {
      float4 zv = *reinterpret_cast<const float4*>(tile + i4 * 4);
      const float* xrow = (row < (long)Ns) ? (state + row * F)
                                           : (edge_attr + (row - Ns) * F);
      float4 xv = *reinterpret_cast<const float4*>(xrow + q * 4);
      float di = rsqrtf(deg[row] + 1.0f);
      v.x = di * (zv.x + di * xv.x);
      v.y = di * (zv.y + di * xv.y);
      v.z = di * (zv.z + di * xv.z);
      v.w = di * (zv.w + di * xv.w);
      *reinterpret_cast<float4*>(y + row * F + q * 4) = v;  // for k_out
    }
    *reinterpret_cast<float4*>(tile + i4 * 4) = v;
  }
  __syncthreads();

  // ---- stats from the LDS tile (round-5 proven form) ----
  if (t < F) {
    float a0 = 0.f, a1 = 0.f, a2 = 0.f, a3 = 0.f;
    for (int r = 0; r < SROWS; r += 4) {
      a0 += tile[(r + 0) * F + t];
      a1 += tile[(r + 1) * F + t];
      a2 += tile[(r + 2) * F + t];
      a3 += tile[(r + 3) * F + t];
    }
    atomicAdd(&stats[t], (a0 + a1) + (a2 + a3));
  } else if (t < NSTAT) {
    int k = t - F, i = 0;
    while (k >= F - i) { k -= F - i; i++; }
    int ci = i, cj = i + k;
    float a0 = 0.f, a1 = 0.f, a2 = 0.f, a3 = 0.f;
    for (int r = 0; r < SROWS; r += 4) {
      a0 += tile[(r + 0) * F + ci] * tile[(r + 0) * F + cj];
      a1 += tile[(r + 1) * F + ci] * tile[(r + 1) * F + cj];
      a2 += tile[(r + 2) * F + ci] * tile[(r + 2) * F + cj];
      a3 += tile[(r + 3) * F + ci] * tile[(r + 3) * F + cj];
    }
    atomicAdd(&stats[t], (a0 + a1) + (a2 + a3));
  }
}

// Single block, 256 threads, launch_bounds(256,1): 4 waves -> up to 512
// VGPR/thread; w[4][20] + m0[20] + m1[20] live in registers (round-4 proven).
__global__ __launch_bounds__(256, 1) void k_finalize(
    const float* __restrict__ stats,
    const float* __restrict__ W_gcn,
    const float* __restrict__ gamma,
    const float* __restrict__ beta,
    const float* __restrict__ W_lin,
    const float* __restrict__ b_lin,
    float* __restrict__ params,
    int N, int H) {
  __shared__ float Cu_s[210];
  __shared__ float ybar_s[F];
  __shared__ float part[4][44];
  int t = threadIdx.x;
  int lane = t & 63;
  int wv = t >> 6;
  float invN = 1.0f / (float)N;
  if (t < F) ybar_s[t] = stats[t] * invN;
  __syncthreads();
  if (t < 210) {
    int k = t, i = 0;
    while (k >= F - i) { k -= F - i; i++; }
    int j = i + k;
    float cv = stats[F + t] * invN - ybar_s[i] * ybar_s[j];
    Cu_s[t] = (i == j) ? cv : 2.0f * cv;  // fold symmetry factor
  }
  __syncthreads();

  float m0[F], m1[F];
  #pragma unroll
  for (int f = 0; f < F; ++f) { m0[f] = 0.f; m1[f] = 0.f; }
  float d0 = 0.f, d1 = 0.f;

  for (int hb = 0; hb < H; hb += 4 * 256) {
    float w[4][F];
    float var[4];
    int hh[4];
    bool act[4];
    #pragma unroll
    for (int c = 0; c < 4; ++c) {
      int h = hb + c * 256 + t;
      act[c] = (h < H);
      hh[c] = act[c] ? h : 0;
      var[c] = 0.f;
      #pragma unroll
      for (int f = 0; f < F; ++f) {
        float x = W_gcn[f * H + hh[c]];  // coalesced over t
        w[c][f] = act[c] ? x : 0.f;
      }
    }
    int p = 0;
    #pragma unroll
    for (int i = 0; i < F; ++i) {
      #pragma unroll
      for (int j = i; j < F; ++j) {
        float cu = Cu_s[p];  // uniform broadcast, reused 4x
        ++p;
        #pragma unroll
        for (int c = 0; c < 4; ++c) var[c] += cu * (w[c][i] * w[c][j]);
      }
    }
    #pragma unroll
    for (int c = 0; c < 4; ++c) {
      float sg = act[c] ? (gamma[hh[c]] * rsqrtf(var[c] + 1e-5f)) : 0.f;
      float wl0 = W_lin[hh[c] * 2 + 0], wl1 = W_lin[hh[c] * 2 + 1];
      float s0 = sg * wl0, s1 = sg * wl1;
      #pragma unroll
      for (int f = 0; f < F; ++f) { m0[f] += w[c][f] * s0; m1[f] += w[c][f] * s1; }
      float bt = act[c] ? beta[hh[c]] : 0.f;
      d0 += bt * wl0;
      d1 += bt * wl1;
    }
  }

  #pragma unroll
  for (int f = 0; f < F; ++f) {
    float v0 = m0[f], v1 = m1[f];
    #pragma unroll
    for (int off = 32; off; off >>= 1) {
      v0 += __shfl_xor(v0, off);
      v1 += __shfl_xor(v1, off);
    }
    if (lane == 0) { part[wv][2 * f] = v0; part[wv][2 * f + 1] = v1; }
  }
  #pragma unroll
  for (int off = 32; off; off >>= 1) {
    d0 += __shfl_xor(d0, off);
    d1 += __shfl_xor(d1, off);
  }
  if (lane == 0) { part[wv][40] = d0; part[wv][41] = d1; }
  __syncthreads();

  if (t < 42) {
    float acc = 0.f;
    for (int w2 = 0; w2 < 4; ++w2) acc += part[w2][t];
    if (t >= 40) acc += b_lin[t - 40];
    params[t] = acc;
  } else if (t < 62) {
    params[t] = ybar_s[t - 42];
  }
}

// thread per node: logits = (y[n]-ybar) @ M + d; relu; 2-way softmax.
__global__ void k_out(const float* __restrict__ y,
                      const float* __restrict__ params,
                      float* __restrict__ out, int N) {
  __shared__ float P[64];
  if (threadIdx.x < 62) P[threadIdx.x] = params[threadIdx.x];
  __syncthreads();
  int n = blockIdx.x * blockDim.x + threadIdx.x;
  if (n >= N) return;
  const float4* yr4 = reinterpret_cast<const float4*>(y + (size_t)n * F);
  float l0 = P[40], l1 = P[41];
  #pragma unroll
  for (int k = 0; k < 5; ++k) {
    float4 q = yr4[k];
    float vv[4] = {q.x, q.y, q.z, q.w};
    #pragma unroll
    for (int u = 0; u < 4; ++u) {
      int f = 4 * k + u;
      float dv = vv[u] - P[42 + f];
      l0 += dv * P[2 * f + 0];
      l1 += dv * P[2 * f + 1];
    }
  }
  l0 = fmaxf(l0, 0.f);
  l1 = fmaxf(l1, 0.f);
  float m = fmaxf(l0, l1);
  float e0 = __expf(l0 - m), e1 = __expf(l1 - m);
  float inv = 1.0f / (e0 + e1);
  float2 o2;
  o2.x = e0 * inv;
  o2.y = e1 * inv;
  reinterpret_cast<float2*>(out)[n] = o2;
}

extern "C" void kernel_launch(void* const* d_in, const int* in_sizes, int n_in,
                              void* d_out, int out_size, void* d_ws, size_t ws_size,
                              hipStream_t stream) {
  const float* state     = (const float*)d_in[0];
  const float* edge_attr = (const float*)d_in[1];
  const int*   eidx      = (const int*)d_in[2];
  const float* W_gcn     = (const float*)d_in[3];
  // d_in[4] = b_gcn: cancels inside batchnorm, unused.
  const float* gamma     = (const float*)d_in[5];
  const float* beta      = (const float*)d_in[6];
  const float* W_lin     = (const float*)d_in[7];
  const float* b_lin     = (const float*)d_in[8];
  float* out = (float*)d_out;

  int Ns = in_sizes[0] / F;
  int E  = in_sizes[2] / 2;
  int N  = Ns + in_sizes[1] / F;
  int H  = in_sizes[4];

  const int* src = eidx;
  const int* dst = eidx + E;

  int NB = (N + SROWS - 1) / SROWS;  // 814 for N=208192 (<=1024 for k_scan)

  float* ws     = (float*)d_ws;
  float* deg    = ws;
  float* y      = ws + N;
  float* stats  = y + (size_t)N * F;
  float* params = stats + 256;
  int*   counts = (int*)(params + 64);
  int*   bstart = counts + NB;
  int*   cursor = bstart + NB + 1;
  int*   ebuf   = cursor + NB;

  k_init<<<(N + BSZ - 1) / BSZ, BSZ, 0, stream>>>(deg, stats, counts, N, NB);
  k_deg_count<<<(E + BSZ - 1) / BSZ, BSZ, 0, stream>>>(dst, deg, counts, E);
  k_scan<<<1, 1024, 0, stream>>>(counts, bstart, cursor, NB, E);
  k_fill<<<(E + BSZ - 1) / BSZ, BSZ, 0, stream>>>(dst, cursor, ebuf, E);
  k_tile<<<NB, BSZ, 0, stream>>>(src, dst, bstart, ebuf, deg, state, edge_attr,
                                 y, stats, N, Ns);
  k_finalize<<<1, 256, 0, stream>>>(stats, W_gcn, gamma, beta, W_lin, b_lin,
                                    params, N, H);
  k_out<<<(N + BSZ - 1) / BSZ, BSZ, 0, stream>>>(y, params, out, N);
}

// Round 16
// 116.132 us; speedup vs baseline: 1.7420x; 1.7420x over previous
//
#include <hip/hip_runtime.h>

// ActorGCN collapsed-linear, split pipeline, 6 dispatches (r12 structure).
// Identity: A(xW) = (Ax)W; BN stats of h = yW+b reduce to the 20x20
// covariance of y = A x. Hidden [N,1024] never materialized.
//
// Round 16 (base r12 = 104.8us best; r15 bucket-tile regressed to 202 —
// ebuf indirection turned all edge-array reads into random gathers):
//  - k_stats: 1024 threads, 4 row-groups x 64 rows -> per-thread serial
//    LDS sweep 512 -> 128 reads, 16 waves/block; partials combined in LDS.
//  - k_scatter: thread per (edge, feature-PAIR): float2 x load + 2 scalar
//    atomics. Pair-major keeps ~6 edges per wave -> per-instruction line
//    locality (r6 lesson: edge-per-lane thrashes L2). Same atomic count,
//    half the index/id load instructions.
// Pipeline: K1 init (y=0,deg=1,stats=0) | K2 deg_acc | K3 scatter |
// K4 stats (self-term fused, y_full writeback, reg-light) | K5 finalize
// (1 block, reg-heavy, launch_bounds(256,1)) | K6 out.
//
// Workspace (floats): deg N | y 20N | stats 256 | params 64.

#define F 20
#define NSTAT 230
#define SROWS 256
#define BSZ 256
#define BSZ_ST 1024

__global__ void k_init(float* __restrict__ deg, float4* __restrict__ y4,
                       float* __restrict__ stats, int N) {
  int i = blockIdx.x * blockDim.x + threadIdx.x;
  if (i < N * 5) y4[i] = make_float4(0.f, 0.f, 0.f, 0.f);
  if (i < N) deg[i] = 1.0f;  // self-loop
  if (i < 256) stats[i] = 0.f;
}

__global__ void k_deg_acc(const int* __restrict__ dst, float* __restrict__ deg, int E) {
  int e = blockIdx.x * blockDim.x + threadIdx.x;
  if (e < E) atomicAdd(&deg[dst[e]], 1.0f);
}

// thread per (edge, pair): y[dst, 2p..2p+1] += norm * x[src, 2p..2p+1].
// e = tid/10 is SEQUENTIAL (r15 lesson: keep edge-array reads coalesced);
// a wave spans ~6.4 edges -> each atomic instruction's 64 ops land on ~7
// cache lines (r6 lesson: one-edge-per-lane destroys this).
__global__ void k_scatter(const int* __restrict__ src, const int* __restrict__ dst,
                          const float* __restrict__ deg,
                          const float* __restrict__ state,
                          const float* __restrict__ edge_attr,
                          float* __restrict__ y, int E, int Ns) {
  int tid = blockIdx.x * blockDim.x + threadIdx.x;
  if (tid >= E * 10) return;
  int e = tid / 10;
  int p = tid - e * 10;
  int s = src[e];
  int d = dst[e];
  float norm = rsqrtf(deg[s]) * rsqrtf(deg[d]);
  const float* xrow = (s < Ns) ? (state + (size_t)s * F)
                               : (edge_attr + (size_t)(s - Ns) * F);
  float2 xv = *reinterpret_cast<const float2*>(xrow + p * 2);
  float* yr = y + (size_t)d * F + p * 2;
  atomicAdd(yr + 0, norm * xv.x);
  atomicAdd(yr + 1, norm * xv.y);
}

// Per 256-row block, 1024 threads: y_full = y_edge + x/deg (writeback for
// k_out), LDS tile, then 4 row-groups of 64 rows compute partial moments in
// parallel (128 LDS reads/thread vs 512 in the 256-thread version); 4
// partials combined in LDS, one global atomicAdd per stat per block.
// Register-light: no arrays, ~30 VGPR, safe at the 1024-thread VGPR cap.
__global__ __launch_bounds__(BSZ_ST) void k_stats(
    const float* __restrict__ state, const float* __restrict__ edge_attr,
    const float* __restrict__ deg, float* __restrict__ y,
    float* __restrict__ stats, int N, int Ns) {
  __shared__ float lds[SROWS * F];   // 20 KB
  __shared__ float pp[4][NSTAT];     // 3.7 KB partials
  int t = threadIdx.x;

  long rowbase = (long)blockIdx.x * SROWS;
  for (int i4 = t; i4 < SROWS * 5; i4 += BSZ_ST) {
    int rl = i4 / 5;
    int q = i4 - rl * 5;
    long row = rowbase + rl;
    float4 v = make_float4(0.f, 0.f, 0.f, 0.f);
    if (row < N) {
      long gi = row * F + q * 4;
      float4 ye = *reinterpret_cast<const float4*>(y + gi);
      const float* xrow = (row < (long)Ns) ? (state + row * F)
                                           : (edge_attr + (row - Ns) * F);
      float4 xv = *reinterpret_cast<const float4*>(xrow + q * 4);
      float di = 1.0f / deg[row];  // self-loop term x/deg
      v.x = ye.x + xv.x * di;
      v.y = ye.y + xv.y * di;
      v.z = ye.z + xv.z * di;
      v.w = ye.w + xv.w * di;
      *reinterpret_cast<float4*>(y + gi) = v;  // y_full for k_out
    }
    *reinterpret_cast<float4*>(lds + i4 * 4) = v;
  }
  __syncthreads();

  int g = t >> 8;       // row group 0..3 -> rows [g*64, g*64+64)
  int c = t & 255;      // stat index within group
  int r0 = g * 64;
  if (c < F) {
    float a0 = 0.f, a1 = 0.f, a2 = 0.f, a3 = 0.f;
    for (int r = r0; r < r0 + 64; r += 4) {
      a0 += lds[(r + 0) * F + c];
      a1 += lds[(r + 1) * F + c];
      a2 += lds[(r + 2) * F + c];
      a3 += lds[(r + 3) * F + c];
    }
    pp[g][c] = (a0 + a1) + (a2 + a3);
  } else if (c < NSTAT) {
    int k = c - F, i = 0;
    while (k >= F - i) { k -= F - i; i++; }
    int ci = i, cj = i + k;
    float a0 = 0.f, a1 = 0.f, a2 = 0.f, a3 = 0.f;
    for (int r = r0; r < r0 + 64; r += 4) {
      a0 += lds[(r + 0) * F + ci] * lds[(r + 0) * F + cj];
      a1 += lds[(r + 1) * F + ci] * lds[(r + 1) * F + cj];
      a2 += lds[(r + 2) * F + ci] * lds[(r + 2) * F + cj];
      a3 += lds[(r + 3) * F + ci] * lds[(r + 3) * F + cj];
    }
    pp[g][c] = (a0 + a1) + (a2 + a3);
  }
  __syncthreads();
  if (t < NSTAT)
    atomicAdd(&stats[t], (pp[0][t] + pp[1][t]) + (pp[2][t] + pp[3][t]));
}

// Single block, 256 threads, launch_bounds(256,1): 4 waves -> up to 512
// VGPR/thread; w[4][20] + m0[20] + m1[20] live in registers (round-4 proven).
__global__ __launch_bounds__(256, 1) void k_finalize(
    const float* __restrict__ stats,
    const float* __restrict__ W_gcn,
    const float* __restrict__ gamma,
    const float* __restrict__ beta,
    const float* __restrict__ W_lin,
    const float* __restrict__ b_lin,
    float* __restrict__ params,
    int N, int H) {
  __shared__ float Cu_s[210];
  __shared__ float ybar_s[F];
  __shared__ float part[4][44];
  int t = threadIdx.x;
  int lane = t & 63;
  int wv = t >> 6;
  float invN = 1.0f / (float)N;
  if (t < F) ybar_s[t] = stats[t] * invN;
  __syncthreads();
  if (t < 210) {
    int k = t, i = 0;
    while (k >= F - i) { k -= F - i; i++; }
    int j = i + k;
    float cv = stats[F + t] * invN - ybar_s[i] * ybar_s[j];
    Cu_s[t] = (i == j) ? cv : 2.0f * cv;  // fold symmetry factor
  }
  __syncthreads();

  float m0[F], m1[F];
  #pragma unroll
  for (int f = 0; f < F; ++f) { m0[f] = 0.f; m1[f] = 0.f; }
  float d0 = 0.f, d1 = 0.f;

  for (int hb = 0; hb < H; hb += 4 * 256) {
    float w[4][F];
    float var[4];
    int hh[4];
    bool act[4];
    #pragma unroll
    for (int c = 0; c < 4; ++c) {
      int h = hb + c * 256 + t;
      act[c] = (h < H);
      hh[c] = act[c] ? h : 0;
      var[c] = 0.f;
      #pragma unroll
      for (int f = 0; f < F; ++f) {
        float x = W_gcn[f * H + hh[c]];  // coalesced over t
        w[c][f] = act[c] ? x : 0.f;
      }
    }
    int p = 0;
    #pragma unroll
    for (int i = 0; i < F; ++i) {
      #pragma unroll
      for (int j = i; j < F; ++j) {
        float cu = Cu_s[p];  // uniform broadcast, reused 4x
        ++p;
        #pragma unroll
        for (int c = 0; c < 4; ++c) var[c] += cu * (w[c][i] * w[c][j]);
      }
    }
    #pragma unroll
    for (int c = 0; c < 4; ++c) {
      float sg = act[c] ? (gamma[hh[c]] * rsqrtf(var[c] + 1e-5f)) : 0.f;
      float wl0 = W_lin[hh[c] * 2 + 0], wl1 = W_lin[hh[c] * 2 + 1];
      float s0 = sg * wl0, s1 = sg * wl1;
      #pragma unroll
      for (int f = 0; f < F; ++f) { m0[f] += w[c][f] * s0; m1[f] += w[c][f] * s1; }
      float bt = act[c] ? beta[hh[c]] : 0.f;
      d0 += bt * wl0;
      d1 += bt * wl1;
    }
  }

  #pragma unroll
  for (int f = 0; f < F; ++f) {
    float v0 = m0[f], v1 = m1[f];
    #pragma unroll
    for (int off = 32; off; off >>= 1) {
      v0 += __shfl_xor(v0, off);
      v1 += __shfl_xor(v1, off);
    }
    if (lane == 0) { part[wv][2 * f] = v0; part[wv][2 * f + 1] = v1; }
  }
  #pragma unroll
  for (int off = 32; off; off >>= 1) {
    d0 += __shfl_xor(d0, off);
    d1 += __shfl_xor(d1, off);
  }
  if (lane == 0) { part[wv][40] = d0; part[wv][41] = d1; }
  __syncthreads();

  if (t < 42) {
    float acc = 0.f;
    for (int w2 = 0; w2 < 4; ++w2) acc += part[w2][t];
    if (t >= 40) acc += b_lin[t - 40];
    params[t] = acc;
  } else if (t < 62) {
    params[t] = ybar_s[t - 42];
  }
}

// thread per node: logits = (y[n]-ybar) @ M + d; relu; 2-way softmax.
__global__ void k_out(const float* __restrict__ y,
                      const float* __restrict__ params,
                      float* __restrict__ out, int N) {
  __shared__ float P[64];
  if (threadIdx.x < 62) P[threadIdx.x] = params[threadIdx.x];
  __syncthreads();
  int n = blockIdx.x * blockDim.x + threadIdx.x;
  if (n >= N) return;
  const float4* yr4 = reinterpret_cast<const float4*>(y + (size_t)n * F);
  float l0 = P[40], l1 = P[41];
  #pragma unroll
  for (int k = 0; k < 5; ++k) {
    float4 q = yr4[k];
    float vv[4] = {q.x, q.y, q.z, q.w};
    #pragma unroll
    for (int u = 0; u < 4; ++u) {
      int f = 4 * k + u;
      float dv = vv[u] - P[42 + f];
      l0 += dv * P[2 * f + 0];
      l1 += dv * P[2 * f + 1];
    }
  }
  l0 = fmaxf(l0, 0.f);
  l1 = fmaxf(l1, 0.f);
  float m = fmaxf(l0, l1);
  float e0 = __expf(l0 - m), e1 = __expf(l1 - m);
  float inv = 1.0f / (e0 + e1);
  float2 o2;
  o2.x = e0 * inv;
  o2.y = e1 * inv;
  reinterpret_cast<float2*>(out)[n] = o2;
}

extern "C" void kernel_launch(void* const* d_in, const int* in_sizes, int n_in,
                              void* d_out, int out_size, void* d_ws, size_t ws_size,
                              hipStream_t stream) {
  const float* state     = (const float*)d_in[0];
  const float* edge_attr = (const float*)d_in[1];
  const int*   eidx      = (const int*)d_in[2];
  const float* W_gcn     = (const float*)d_in[3];
  // d_in[4] = b_gcn: cancels inside batchnorm, unused.
  const float* gamma     = (const float*)d_in[5];
  const float* beta      = (const float*)d_in[6];
  const float* W_lin     = (const float*)d_in[7];
  const float* b_lin     = (const float*)d_in[8];
  float* out = (float*)d_out;

  int Ns = in_sizes[0] / F;
  int E  = in_sizes[2] / 2;
  int N  = Ns + in_sizes[1] / F;
  int H  = in_sizes[4];

  const int* src = eidx;
  const int* dst = eidx + E;

  float* ws     = (float*)d_ws;
  float* deg    = ws;
  float* y      = ws + N;
  float* stats  = y + (size_t)N * F;
  float* params = stats + 256;

  int nblk = (N + SROWS - 1) / SROWS;

  k_init<<<(N * 5 + BSZ - 1) / BSZ, BSZ, 0, stream>>>(deg, (float4*)y, stats, N);
  k_deg_acc<<<(E + BSZ - 1) / BSZ, BSZ, 0, stream>>>(dst, deg, E);
  k_scatter<<<(E * 10 + BSZ - 1) / BSZ, BSZ, 0, stream>>>(
      src, dst, deg, state, edge_attr, y, E, Ns);
  k_stats<<<nblk, BSZ_ST, 0, stream>>>(state, edge_attr, deg, y, stats, N, Ns);
  k_finalize<<<1, 256, 0, stream>>>(stats, W_gcn, gamma, beta, W_lin, b_lin,
                                    params, N, H);
  k_out<<<(N + BSZ - 1) / BSZ, BSZ, 0, stream>>>(y, params, out, N);
}